// Round 1
// baseline (680.505 us; speedup 1.0000x reference)
//
#include <hip/hip_runtime.h>
#include <hip/hip_fp16.h>

#define N_NODES 50000
#define N_EDGES 600000

typedef _Float16 f16x8 __attribute__((ext_vector_type(8)));
typedef _Float16 f16x4 __attribute__((ext_vector_type(4)));
typedef float f32x4 __attribute__((ext_vector_type(4)));

// ws layout (offsets in halfs):
//   w1ab : [512][128]  (n<256: W1[n][k] ; n>=256: W1[n-256][128+k])
//   w1c  : [256][128]  (W1[n][256+k])
//   w2h  : [128][256]  (W2[n][k])
//   xab  : [50048][512] (node precompute: x[v] @ [W1a;W1b]^T, fp16)
#define W1AB_OFF 0
#define W1C_OFF  65536
#define W2_OFF   98304
#define XAB_OFF  131072
// total halfs = 131072 + 50048*512 = 25755648  (~51.5 MB)

// ---------------------------------------------------------------------------
// P0: convert weights fp32 -> fp16, repacked (unchanged)
__global__ __launch_bounds__(256) void convert_weights(
    const float* __restrict__ W1, const float* __restrict__ W2,
    _Float16* __restrict__ ws16) {
  int i = blockIdx.x * 256 + threadIdx.x;  // 0 .. 131071
  if (i < 65536) {                         // w1ab
    int n = i >> 7, k = i & 127;
    float v = (n < 256) ? W1[n * 384 + k] : W1[(n - 256) * 384 + 128 + k];
    ws16[W1AB_OFF + i] = (_Float16)v;
  } else if (i < 98304) {                  // w1c
    int j = i - 65536;
    int n = j >> 7, k = j & 127;
    ws16[W1C_OFF + j] = (_Float16)W1[n * 384 + 256 + k];
  } else {                                 // w2
    int j = i - 98304;
    ws16[W2_OFF + j] = (_Float16)W2[j];
  }
}

// ---------------------------------------------------------------------------
// P1: per-node precompute, SWAPPED operands: D = W1ab * x^T
//   D[n][node] -> lane holds 4 contiguous n per reg -> f16x4 stores
__global__ __launch_bounds__(256, 2) void node_precompute(
    const float* __restrict__ x, _Float16* __restrict__ ws16) {
  const _Float16* __restrict__ w1ab = ws16 + W1AB_OFF;
  _Float16* __restrict__ xab = ws16 + XAB_OFF;

  __shared__ __align__(16) _Float16 xt[64][136];  // +8 halfs pad
  int tid = threadIdx.x;
  int v0 = blockIdx.x * 64;

  // stage x tile (fp32 -> fp16), rows clamped for last partial block
#pragma unroll
  for (int it = 0; it < 8; ++it) {
    int f = tid + it * 256;          // float4 id, 2048 total
    int r = f >> 5;                  // 32 float4 per row
    int c = (f & 31) * 4;
    int vr = v0 + r;
    if (vr > N_NODES - 1) vr = N_NODES - 1;
    float4 val = *(const float4*)&x[(size_t)vr * 128 + c];
    f16x4 h;
    h[0] = (_Float16)val.x; h[1] = (_Float16)val.y;
    h[2] = (_Float16)val.z; h[3] = (_Float16)val.w;
    *(f16x4*)&xt[r][c] = h;
  }
  __syncthreads();

  int lane = tid & 63;
  int w = __builtin_amdgcn_readfirstlane(tid >> 6);  // wave id 0..3
  int m16 = lane & 15;
  int quad = lane >> 4;

  for (int nn = 0; nn < 2; ++nn) {
    f32x4 acc[4][4] = {};
#pragma unroll
    for (int kk = 0; kk < 4; ++kk) {
      f16x8 av[4], bv[4];
#pragma unroll
      for (int mb = 0; mb < 4; ++mb)  // A = w1ab rows (n dim)
        av[mb] = *(const f16x8*)&w1ab[(size_t)(w * 128 + nn * 64 + mb * 16 + m16) * 128 +
                                      kk * 32 + quad * 8];
#pragma unroll
      for (int nb = 0; nb < 4; ++nb)  // B = x^T (node dim)
        bv[nb] = *(const f16x8*)&xt[nb * 16 + m16][kk * 32 + quad * 8];
#pragma unroll
      for (int mb = 0; mb < 4; ++mb)
#pragma unroll
        for (int nb = 0; nb < 4; ++nb)
          acc[mb][nb] = __builtin_amdgcn_mfma_f32_16x16x32_f16(av[mb], bv[nb], acc[mb][nb], 0, 0, 0);
    }
    // D: row = n = nn*64 + mb*16 + quad*4 + r (contig in r), col = node = nb*16 + m16
#pragma unroll
    for (int mb = 0; mb < 4; ++mb)
#pragma unroll
      for (int nb = 0; nb < 4; ++nb) {
        int v = v0 + nb * 16 + m16;
        if (v < N_NODES) {
          f16x4 hh;
#pragma unroll
          for (int r = 0; r < 4; ++r) hh[r] = (_Float16)acc[mb][nb][r];
          int n = w * 128 + nn * 64 + mb * 16 + quad * 4;
          *(f16x4*)&xab[(size_t)v * 512 + n] = hh;
        }
      }
  }
}

// ---------------------------------------------------------------------------
// Main fused kernel: 64 edges per block, 4 waves. SWAPPED operands both phases:
//   phase1: D1 = W1c * ea^T    (M=256 n1 over 4 waves, N=64 edges, K=128)
//   epi1  : h = relu(D1 + s) written n1-contiguous (f16x4 LDS ops)
//   phase2: D2 = W2 * h^T      (M=128 n2 over 4 waves, N=64 edges, K=256)
//   epi2  : out[edge][n2] via float4 stores
__global__ __launch_bounds__(256, 3) void edge_mlp(
    const int* __restrict__ ei, const float* __restrict__ ea,
    const float* __restrict__ b1, const float* __restrict__ b2,
    const _Float16* __restrict__ ws16, float* __restrict__ out) {
  const _Float16* __restrict__ w1c = ws16 + W1C_OFF;
  const _Float16* __restrict__ w2h = ws16 + W2_OFF;
  const _Float16* __restrict__ xab = ws16 + XAB_OFF;

  __shared__ __align__(16) _Float16 eat[64][136];  // ea tile, +8 pad (17408 B)
  __shared__ __align__(16) _Float16 sh[64][264];   // s then h (aliased), +8 pad (33792 B)

  int tid = threadIdx.x;
  int e0 = blockIdx.x * 64;
  int lane = tid & 63;
  int w = __builtin_amdgcn_readfirstlane(tid >> 6);  // wave id, SGPR
  int m16 = lane & 15;
  int quad = lane >> 4;

  // stage ea tile (fp32 -> fp16)
#pragma unroll
  for (int it = 0; it < 8; ++it) {
    int f = tid + it * 256;
    int r = f >> 5;
    int c = (f & 31) * 4;
    float4 val = *(const float4*)&ea[(size_t)(e0 + r) * 128 + c];
    f16x4 h;
    h[0] = (_Float16)val.x; h[1] = (_Float16)val.y;
    h[2] = (_Float16)val.z; h[3] = (_Float16)val.w;
    *(f16x4*)&eat[r][c] = h;
  }

  // wave-uniform scalar loads of this wave's 16 edge index pairs (s_load path)
  int vr[16], vc[16];
#pragma unroll
  for (int i = 0; i < 16; ++i) {
    int a = ei[e0 + w * 16 + i];
    int b = ei[N_EDGES + e0 + w * 16 + i];
    if (a < 0) a = 0;
    if (a > N_NODES - 1) a = N_NODES - 1;
    if (b < 0) b = 0;
    if (b > N_NODES - 1) b = N_NODES - 1;
    vr[i] = a;
    vc[i] = b;
  }

  // batch-issue ALL 32 gathers (one latency exposure, not four)
  f16x4 ga[16], gb[16];
#pragma unroll
  for (int i = 0; i < 16; ++i) {
    ga[i] = *(const f16x4*)&xab[(size_t)vr[i] * 512 + lane * 4];
    gb[i] = *(const f16x4*)&xab[(size_t)vc[i] * 512 + 256 + lane * 4];
  }
  f16x4 b1h;
  {
    float4 bb = *(const float4*)&b1[lane * 4];
    b1h[0] = (_Float16)bb.x; b1h[1] = (_Float16)bb.y;
    b1h[2] = (_Float16)bb.z; b1h[3] = (_Float16)bb.w;
  }
  // consume: s = xa + xb + b1 (packed f16 adds), stage to LDS
#pragma unroll
  for (int i = 0; i < 16; ++i) {
    f16x4 s = ga[i] + gb[i] + b1h;
    *(f16x4*)&sh[w * 16 + i][lane * 4] = s;
  }
  __syncthreads();

  // phase 1: D1 = W1c * ea^T ; wave w owns n1 in [w*64, w*64+64)
  f32x4 acc[4][4] = {};
#pragma unroll
  for (int kk = 0; kk < 4; ++kk) {
    f16x8 av[4], bv[4];
#pragma unroll
    for (int mb = 0; mb < 4; ++mb)  // A = w1c rows (n1)
      av[mb] = *(const f16x8*)&w1c[(size_t)(w * 64 + mb * 16 + m16) * 128 + kk * 32 + quad * 8];
#pragma unroll
    for (int eb = 0; eb < 4; ++eb)  // B = ea^T (edge cols)
      bv[eb] = *(const f16x8*)&eat[eb * 16 + m16][kk * 32 + quad * 8];
#pragma unroll
    for (int mb = 0; mb < 4; ++mb)
#pragma unroll
      for (int eb = 0; eb < 4; ++eb)
        acc[mb][eb] = __builtin_amdgcn_mfma_f32_16x16x32_f16(av[mb], bv[eb], acc[mb][eb], 0, 0, 0);
  }

  // epilogue 1: h = relu(acc + s), IN PLACE, n1-contiguous per lane (b64 LDS ops)
  // D1: row = n1 = w*64 + mb*16 + quad*4 + r, col = edge = eb*16 + m16
#pragma unroll
  for (int mb = 0; mb < 4; ++mb)
#pragma unroll
    for (int eb = 0; eb < 4; ++eb) {
      _Float16* p = &sh[eb * 16 + m16][w * 64 + mb * 16 + quad * 4];
      f16x4 s4 = *(const f16x4*)p;
      f16x4 hh;
#pragma unroll
      for (int r = 0; r < 4; ++r) {
        float v = acc[mb][eb][r] + (float)s4[r];
        hh[r] = (_Float16)(v > 0.f ? v : 0.f);
      }
      *(f16x4*)p = hh;
    }
  __syncthreads();

  // phase 2: D2 = W2 * h^T ; wave w owns n2 in [w*32, w*32+32)
  f32x4 acc2[2][4] = {};
#pragma unroll
  for (int kk = 0; kk < 8; ++kk) {
    f16x8 av[2], bv[4];
#pragma unroll
    for (int mb = 0; mb < 2; ++mb)  // A = w2 rows (n2)
      av[mb] = *(const f16x8*)&w2h[(size_t)(w * 32 + mb * 16 + m16) * 256 + kk * 32 + quad * 8];
#pragma unroll
    for (int eb = 0; eb < 4; ++eb)  // B = h^T (edge cols)
      bv[eb] = *(const f16x8*)&sh[eb * 16 + m16][kk * 32 + quad * 8];
#pragma unroll
    for (int mb = 0; mb < 2; ++mb)
#pragma unroll
      for (int eb = 0; eb < 4; ++eb)
        acc2[mb][eb] = __builtin_amdgcn_mfma_f32_16x16x32_f16(av[mb], bv[eb], acc2[mb][eb], 0, 0, 0);
  }

  // epilogue 2: out = acc2 + b2 via float4 stores
  // D2: row = n2 = w*32 + mb*16 + quad*4 + r, col = edge = eb*16 + m16
  float4 bb2[2];
  bb2[0] = *(const float4*)&b2[w * 32 + quad * 4];
  bb2[1] = *(const float4*)&b2[w * 32 + 16 + quad * 4];
#pragma unroll
  for (int mb = 0; mb < 2; ++mb)
#pragma unroll
    for (int eb = 0; eb < 4; ++eb) {
      float4 o;
      o.x = acc2[mb][eb][0] + bb2[mb].x;
      o.y = acc2[mb][eb][1] + bb2[mb].y;
      o.z = acc2[mb][eb][2] + bb2[mb].z;
      o.w = acc2[mb][eb][3] + bb2[mb].w;
      *(float4*)&out[(size_t)(e0 + eb * 16 + m16) * 128 + w * 32 + mb * 16 + quad * 4] = o;
    }
}

// ---------------------------------------------------------------------------
extern "C" void kernel_launch(void* const* d_in, const int* in_sizes, int n_in,
                              void* d_out, int out_size, void* d_ws, size_t ws_size,
                              hipStream_t stream) {
  const float* x  = (const float*)d_in[0];
  const int*   ei = (const int*)d_in[1];
  const float* ea = (const float*)d_in[2];
  const float* W1 = (const float*)d_in[3];
  const float* b1 = (const float*)d_in[4];
  const float* W2 = (const float*)d_in[5];
  const float* b2 = (const float*)d_in[6];
  float* out = (float*)d_out;
  _Float16* ws16 = (_Float16*)d_ws;

  convert_weights<<<512, 256, 0, stream>>>(W1, W2, ws16);
  node_precompute<<<(N_NODES + 63) / 64, 256, 0, stream>>>(x, ws16);
  edge_mlp<<<N_EDGES / 64, 256, 0, stream>>>(ei, ea, b1, b2, ws16, out);
}